// Round 1
// baseline (255.463 us; speedup 1.0000x reference)
//
#include <hip/hip_runtime.h>
#include <math.h>

#define B_DIM 4
#define L_DIM 8192
#define H_DIM 256
#define P_DIM 256
#define M_DIM (B_DIM * L_DIM)   // 32768 rows (b,l) flattened
#define NC 64                   // scan chunks per chain
#define LC 128                  // chunk length (NC*LC = L)

typedef __attribute__((ext_vector_type(8))) short bf16x8;
typedef __attribute__((ext_vector_type(4))) float f32x4;
typedef __attribute__((ext_vector_type(8))) unsigned short u16x8;

static __device__ __forceinline__ float bf2f(unsigned short u) {
    union { unsigned int i; float f; } v; v.i = ((unsigned int)u) << 16; return v.f;
}
static __device__ __forceinline__ unsigned short f2bf(float f) {
    union { float f; unsigned int i; } v; v.f = f;
    unsigned int r = v.i + 0x7FFFu + ((v.i >> 16) & 1u);
    return (unsigned short)(r >> 16);
}
// tanh-form GELU; |gelu_tanh - gelu_erf| <= ~0.003 absolute, far under 0.26 threshold
static __device__ __forceinline__ float gelu_f(float x) {
    float z = 0.7978845608028654f * (x + 0.044715f * x * x * x);
    float e = __expf(2.0f * z);
    float t = 1.0f - 2.0f / (e + 1.0f);   // tanh(z), saturates correctly at +/-inf
    return 0.5f * x * (1.0f + t);
}

// ---------------- prep kernels ----------------

// Bmat[(g*256+p)*256 + h], g = dir*2 + comp, bf16.  B_bar per discretize().
__global__ void bbar_kernel(const float* fLr, const float* fIm, const float* fLd,
                            const float* fBr, const float* fBi,
                            const float* bLr, const float* bIm, const float* bLd,
                            const float* bBr, const float* bBi,
                            unsigned short* Bmat) {
    int gid = blockIdx.x * 256 + threadIdx.x;   // 0..262143
    int g = gid >> 16;
    int p = (gid >> 8) & 255;
    int h = gid & 255;
    int dir = g >> 1, comp = g & 1;
    const float* LR = dir ? bLr : fLr;
    const float* IM = dir ? bIm : fIm;
    const float* LD = dir ? bLd : fLd;
    const float* BR = dir ? bBr : fBr;
    const float* BI = dir ? bBi : fBi;
    float Lr = -expf(LR[p]);
    float Li = IM[p];
    float Delta = expf(LD[p]);
    float ea = expf(Lr * Delta);
    float bd = Li * Delta;
    float Lbr = ea * cosf(bd);
    float Lbi = ea * sinf(bd);
    float denom = fmaxf(Lr * Lr + Li * Li, 1e-12f);
    float ivr = Lr / denom, ivi = -Li / denom;
    float dr = Lbr - 1.0f, di = Lbi;
    float cr = ivr * dr - ivi * di;
    float ci = ivr * di + ivi * dr;
    float br = BR[p * 256 + h], bi = BI[p * 256 + h];
    float val = comp ? (cr * bi + ci * br) : (cr * br - ci * bi);
    Bmat[gid] = f2bf(val);
}

// LbarWS[dir*256+p] = (Lbar_r, Lbar_i) fp32
__global__ void lbar_kernel(const float* fLr, const float* fIm, const float* fLd,
                            const float* bLr, const float* bIm, const float* bLd,
                            float2* LbarWS) {
    int gid = blockIdx.x * 256 + threadIdx.x;  // 0..511
    int dir = gid >> 8; int p = gid & 255;
    const float* LR = dir ? bLr : fLr;
    const float* IM = dir ? bIm : fIm;
    const float* LD = dir ? bLd : fLd;
    float Lr = -expf(LR[p]); float Li = IM[p]; float Delta = expf(LD[p]);
    float ea = expf(Lr * Delta); float bd = Li * Delta;
    LbarWS[gid] = make_float2(ea * cosf(bd), ea * sinf(bd));
}

// B3[(d*256+h)*512 + k]: k<256 -> C_real[h][k]; else -> -C_imag[h][k-256]  (bf16)
__global__ void c3_kernel(const float* fCr, const float* fCi,
                          const float* bCr, const float* bCi,
                          unsigned short* B3) {
    int gid = blockIdx.x * 256 + threadIdx.x;  // 0..262143
    int d = gid >> 17;
    int rem = gid & 131071;
    int h = rem >> 9;
    int k = rem & 511;
    const float* CR = d ? bCr : fCr;
    const float* CI = d ? bCi : fCi;
    float val = (k < 256) ? CR[h * 256 + k] : -CI[h * 256 + (k - 256)];
    B3[gid] = f2bf(val);
}

// x (fp32) -> xbf (bf16)
__global__ void xcast_kernel(const float4* __restrict__ x4, ushort4* __restrict__ xb) {
    int gid = blockIdx.x * 256 + threadIdx.x;  // 0..2097151
    float4 v = x4[gid];
    ushort4 o;
    o.x = f2bf(v.x); o.y = f2bf(v.y); o.z = f2bf(v.z); o.w = f2bf(v.w);
    xb[gid] = o;
}

// ---------------- K1: Bu = xbf(32768x256) @ Bmat(1024x256)^T -> Bu bf16 (32768x1024) ----------------
__global__ __launch_bounds__(512) void k1_gemm(const unsigned short* __restrict__ A,
                                               const unsigned short* __restrict__ Bm,
                                               unsigned short* __restrict__ Bu) {
    __shared__ unsigned short As[128][72];  // +8 pad: 2-way max on b128 reads (free)
    __shared__ unsigned short Bs[128][72];
    int tid = threadIdx.x;
    int lane = tid & 63, w = tid >> 6;
    int wm = (w >> 1) * 32, wn = (w & 1) * 64;
    int Mb = blockIdx.x * 128, Nb = blockIdx.y * 128;
    f32x4 acc[2][4];
#pragma unroll
    for (int i = 0; i < 2; i++)
#pragma unroll
        for (int j = 0; j < 4; j++) acc[i][j] = (f32x4){0.f, 0.f, 0.f, 0.f};
    int r0 = tid >> 3, sg = (tid & 7) * 8;
    int mrow = lane & 15, quad = lane >> 4;
    for (int kb = 0; kb < 256; kb += 64) {
        *(u16x8*)&As[r0][sg]      = *(const u16x8*)(A  + (size_t)(Mb + r0) * 256 + kb + sg);
        *(u16x8*)&As[r0 + 64][sg] = *(const u16x8*)(A  + (size_t)(Mb + r0 + 64) * 256 + kb + sg);
        *(u16x8*)&Bs[r0][sg]      = *(const u16x8*)(Bm + (size_t)(Nb + r0) * 256 + kb + sg);
        *(u16x8*)&Bs[r0 + 64][sg] = *(const u16x8*)(Bm + (size_t)(Nb + r0 + 64) * 256 + kb + sg);
        __syncthreads();
#pragma unroll
        for (int kk = 0; kk < 64; kk += 32) {
            bf16x8 af[2], bfr[4];
#pragma unroll
            for (int i = 0; i < 2; i++) af[i] = *(const bf16x8*)&As[wm + 16 * i + mrow][kk + quad * 8];
#pragma unroll
            for (int j = 0; j < 4; j++) bfr[j] = *(const bf16x8*)&Bs[wn + 16 * j + mrow][kk + quad * 8];
#pragma unroll
            for (int i = 0; i < 2; i++)
#pragma unroll
                for (int j = 0; j < 4; j++)
                    acc[i][j] = __builtin_amdgcn_mfma_f32_16x16x32_bf16(af[i], bfr[j], acc[i][j], 0, 0, 0);
        }
        __syncthreads();
    }
#pragma unroll
    for (int i = 0; i < 2; i++)
#pragma unroll
        for (int j = 0; j < 4; j++)
#pragma unroll
            for (int r = 0; r < 4; r++) {
                int row = Mb + wm + 16 * i + quad * 4 + r;
                int col = Nb + wn + 16 * j + mrow;
                Bu[(size_t)row * 1024 + col] = f2bf(acc[i][j][r]);
            }
}

// ---------------- scan pass 1: per-chunk carries ----------------
// chain = (dir d, batch b, p). fwd: s_l = A s_{l-1} + Z_f[l] ascending.
// bwd: W_l = A W_{l+1} + Z_b[l] descending (this IS the re-flipped backward state).
__global__ void scan_carry_kernel(const unsigned short* __restrict__ XS,
                                  const float2* __restrict__ Lbar,
                                  float2* __restrict__ carry) {
    int c = blockIdx.x, b = blockIdx.y, d = blockIdx.z;
    int p = threadIdx.x;
    float2 A = Lbar[d * 256 + p];
    int g = d * 2;
    float sr = 0.f, si = 0.f;
    if (d == 0) {
        for (int t = 0; t < LC; t++) {
            int l = c * LC + t;
            const unsigned short* ptr = XS + ((size_t)(b * L_DIM + l)) * 1024 + g * 256 + p;
            float zr = bf2f(ptr[0]), zi = bf2f(ptr[256]);
            float nr = A.x * sr - A.y * si + zr;
            float ni = A.x * si + A.y * sr + zi;
            sr = nr; si = ni;
        }
    } else {
        for (int t = LC - 1; t >= 0; t--) {
            int l = c * LC + t;
            const unsigned short* ptr = XS + ((size_t)(b * L_DIM + l)) * 1024 + g * 256 + p;
            float zr = bf2f(ptr[0]), zi = bf2f(ptr[256]);
            float nr = A.x * sr - A.y * si + zr;
            float ni = A.x * si + A.y * sr + zi;
            sr = nr; si = ni;
        }
    }
    carry[((d * 4 + b) * NC + c) * 256 + p] = make_float2(sr, si);
}

// ---------------- scan pass 2: combine carries, rescan chunk, write xs in-place ----------------
__global__ void scan_fix_kernel(unsigned short* __restrict__ XS,
                                const float2* __restrict__ Lbar,
                                const float2* __restrict__ carry) {
    int c = blockIdx.x, b = blockIdx.y, d = blockIdx.z;
    int p = threadIdx.x;
    float2 A = Lbar[d * 256 + p];
    float ar = A.x, ai = A.y;
    float a128r = ar, a128i = ai;
#pragma unroll
    for (int k = 0; k < 7; k++) {  // A^(2^7) = A^128
        float nr = a128r * a128r - a128i * a128i;
        float ni = 2.f * a128r * a128i;
        a128r = nr; a128i = ni;
    }
    float sr = 0.f, si = 0.f;
    const float2* cb = carry + ((size_t)(d * 4 + b) * NC) * 256 + p;
    int g = d * 2;
    if (d == 0) {
        for (int j = 0; j < c; j++) {
            float2 cj = cb[(size_t)j * 256];
            float nr = a128r * sr - a128i * si + cj.x;
            float ni = a128r * si + a128i * sr + cj.y;
            sr = nr; si = ni;
        }
        for (int t = 0; t < LC; t++) {
            int l = c * LC + t;
            unsigned short* ptr = XS + ((size_t)(b * L_DIM + l)) * 1024 + g * 256 + p;
            float zr = bf2f(ptr[0]), zi = bf2f(ptr[256]);
            float nr = ar * sr - ai * si + zr;
            float ni = ar * si + ai * sr + zi;
            sr = nr; si = ni;
            ptr[0] = f2bf(sr); ptr[256] = f2bf(si);
        }
    } else {
        for (int j = NC - 1; j > c; j--) {
            float2 cj = cb[(size_t)j * 256];
            float nr = a128r * sr - a128i * si + cj.x;
            float ni = a128r * si + a128i * sr + cj.y;
            sr = nr; si = ni;
        }
        for (int t = LC - 1; t >= 0; t--) {
            int l = c * LC + t;
            unsigned short* ptr = XS + ((size_t)(b * L_DIM + l)) * 1024 + g * 256 + p;
            float zr = bf2f(ptr[0]), zi = bf2f(ptr[256]);
            float nr = ar * sr - ai * si + zr;
            float ni = ar * si + ai * sr + zi;
            sr = nr; si = ni;
            ptr[0] = f2bf(sr); ptr[256] = f2bf(si);
        }
    }
}

// ---------------- K3: out = gelu(xs_f·Cf + Df*x) + gelu(W·Cb + Db*x) ----------------
__global__ __launch_bounds__(512) void k3_gemm(const unsigned short* __restrict__ XS,
                                               const unsigned short* __restrict__ B3,
                                               const float* __restrict__ x,
                                               const float* __restrict__ Df,
                                               const float* __restrict__ Db,
                                               float* __restrict__ out) {
    __shared__ unsigned short As[128][72];
    __shared__ unsigned short Bs[128][72];
    int tid = threadIdx.x;
    int lane = tid & 63, w = tid >> 6;
    int wm = (w >> 1) * 32, wn = (w & 1) * 64;
    int Mb = blockIdx.x * 128, Hb = blockIdx.y * 128;
    f32x4 accf[2][4], accb[2][4];
#pragma unroll
    for (int i = 0; i < 2; i++)
#pragma unroll
        for (int j = 0; j < 4; j++) {
            accf[i][j] = (f32x4){0.f, 0.f, 0.f, 0.f};
            accb[i][j] = (f32x4){0.f, 0.f, 0.f, 0.f};
        }
    int r0 = tid >> 3, sg = (tid & 7) * 8;
    int mrow = lane & 15, quad = lane >> 4;
    for (int half = 0; half < 2; half++) {
        f32x4 (*acc)[4] = half ? accb : accf;
        const unsigned short* Bh = B3 + (size_t)half * 131072;
        int coff = half * 512;
        for (int kb = 0; kb < 512; kb += 64) {
            *(u16x8*)&As[r0][sg]      = *(const u16x8*)(XS + (size_t)(Mb + r0) * 1024 + coff + kb + sg);
            *(u16x8*)&As[r0 + 64][sg] = *(const u16x8*)(XS + (size_t)(Mb + r0 + 64) * 1024 + coff + kb + sg);
            *(u16x8*)&Bs[r0][sg]      = *(const u16x8*)(Bh + (size_t)(Hb + r0) * 512 + kb + sg);
            *(u16x8*)&Bs[r0 + 64][sg] = *(const u16x8*)(Bh + (size_t)(Hb + r0 + 64) * 512 + kb + sg);
            __syncthreads();
#pragma unroll
            for (int kk = 0; kk < 64; kk += 32) {
                bf16x8 af[2], bfr[4];
#pragma unroll
                for (int i = 0; i < 2; i++) af[i] = *(const bf16x8*)&As[wm + 16 * i + mrow][kk + quad * 8];
#pragma unroll
                for (int j = 0; j < 4; j++) bfr[j] = *(const bf16x8*)&Bs[wn + 16 * j + mrow][kk + quad * 8];
#pragma unroll
                for (int i = 0; i < 2; i++)
#pragma unroll
                    for (int j = 0; j < 4; j++)
                        acc[i][j] = __builtin_amdgcn_mfma_f32_16x16x32_bf16(af[i], bfr[j], acc[i][j], 0, 0, 0);
            }
            __syncthreads();
        }
    }
#pragma unroll
    for (int i = 0; i < 2; i++)
#pragma unroll
        for (int j = 0; j < 4; j++) {
            int h = Hb + wn + 16 * j + mrow;
            float df = Df[h], db = Db[h];
#pragma unroll
            for (int r = 0; r < 4; r++) {
                int row = Mb + wm + 16 * i + quad * 4 + r;
                float xv = x[(size_t)row * 256 + h];
                float yf = accf[i][j][r] + df * xv;
                float yb = accb[i][j][r] + db * xv;
                out[(size_t)row * 256 + h] = gelu_f(yf) + gelu_f(yb);
            }
        }
}

// ---------------- launcher ----------------
extern "C" void kernel_launch(void* const* d_in, const int* in_sizes, int n_in,
                              void* d_out, int out_size, void* d_ws, size_t ws_size,
                              hipStream_t stream) {
    const float* x   = (const float*)d_in[0];
    const float* fLr = (const float*)d_in[1];
    const float* fIm = (const float*)d_in[2];
    const float* fLd = (const float*)d_in[3];
    const float* fBr = (const float*)d_in[4];
    const float* fBi = (const float*)d_in[5];
    const float* fCr = (const float*)d_in[6];
    const float* fCi = (const float*)d_in[7];
    const float* fD  = (const float*)d_in[8];
    const float* bLr = (const float*)d_in[9];
    const float* bIm = (const float*)d_in[10];
    const float* bLd = (const float*)d_in[11];
    const float* bBr = (const float*)d_in[12];
    const float* bBi = (const float*)d_in[13];
    const float* bCr = (const float*)d_in[14];
    const float* bCi = (const float*)d_in[15];
    const float* bD  = (const float*)d_in[16];
    float* out = (float*)d_out;

    char* ws = (char*)d_ws;
    unsigned short* xbf  = (unsigned short*)(ws);                               // 16 MiB
    unsigned short* Bu   = (unsigned short*)(ws + 16777216);                    // 64 MiB (Bu, then xs in-place)
    unsigned short* Bmat = (unsigned short*)(ws + 16777216 + 67108864);         // 512 KiB
    unsigned short* B3   = (unsigned short*)(ws + 16777216 + 67108864 + 524288);// 512 KiB
    float2* LbarWS = (float2*)(ws + 16777216 + 67108864 + 1048576);             // 4 KiB
    float2* carry  = (float2*)(ws + 16777216 + 67108864 + 1048576 + 4096);      // 1 MiB

    bbar_kernel<<<1024, 256, 0, stream>>>(fLr, fIm, fLd, fBr, fBi, bLr, bIm, bLd, bBr, bBi, Bmat);
    c3_kernel<<<1024, 256, 0, stream>>>(fCr, fCi, bCr, bCi, B3);
    lbar_kernel<<<2, 256, 0, stream>>>(fLr, fIm, fLd, bLr, bIm, bLd, LbarWS);
    xcast_kernel<<<8192, 256, 0, stream>>>((const float4*)x, (ushort4*)xbf);
    k1_gemm<<<dim3(256, 8), 512, 0, stream>>>(xbf, Bmat, Bu);
    scan_carry_kernel<<<dim3(NC, 4, 2), 256, 0, stream>>>(Bu, LbarWS, carry);
    scan_fix_kernel<<<dim3(NC, 4, 2), 256, 0, stream>>>(Bu, LbarWS, carry);
    k3_gemm<<<dim3(256, 2), 512, 0, stream>>>(Bu, B3, x, fD, bD, out);
}